// Round 10
// baseline (146.657 us; speedup 1.0000x reference)
//
#include <hip/hip_runtime.h>

// SSIM (B=16, C=3, H=W=512, fp32) -> scalar mean.
// v10: v9 with a size-preserving pure-XOR LDS swizzle  P = E ^ ((E>>4)&3).
//  Enumerated per 16-lane phase:
//   - reads  (element stride 4): P mod 16 = l0<<2 | (c^l1)  -> injective -> conflict-free
//   - writes (element stride 2): P mod 16 = rotate(l)        -> injective -> conflict-free
//  XOR keys bits[1:0] on bits[5:4]: bijective on 4-aligned ranges, no size
//  inflation -> LDS back to 33 KB -> 4 blocks/CU (was 3 at 42.5 KB).
//  Everything else identical to v9 (4-row steps, col-pair vertical ring,
//  col-quad horizontal, packed fp32, fused atomicAdd reduction).

typedef float v2f __attribute__((ext_vector_type(2)));

#define IMG_H 512
#define IMG_W 512
#define N_IMG 48                    // B*C
#define WS 11
#define PAD 5
#define CHUNK 16                    // output rows per block
#define NCHUNK (IMG_H / CHUNK)      // 32
#define RING 14                     // rows held in registers
#define PLANE_B 4224                // bytes per (pair,plane) region (max P < 528)
#define INV_NPX (1.0f / (48.0f * 512.0f * 512.0f))

// swizzled byte offset of element E (element = 8B v2f {row_even,row_odd})
__device__ __forceinline__ unsigned swz8(int E) {
    return (unsigned)((E ^ ((E >> 4) & 3)) * 8);
}
__device__ __forceinline__ v2f vfma(v2f a, v2f b, v2f c) {
    return __builtin_elementwise_fma(a, b, c);
}

__global__ __launch_bounds__(256, 4) void ssim_partial_kernel(
    const float* __restrict__ img1,
    const float* __restrict__ img2,
    const float* __restrict__ window,
    float* __restrict__ out)
{
    __shared__ __align__(16) char lds[8 * PLANE_B];   // region (pair*4+plane)
    __shared__ float wred[4];

    const int tid = threadIdx.x;
    const int bc  = blockIdx.x;              // image*channel 0..47
    const int r0  = blockIdx.y * CHUNK;
    const int col = tid * 2;                 // vertical ownership: cols col,col+1

    // 1-D gaussian from window row 5: w2d[5][j] = g5*g[j], g5 = sqrt(w2d[5][5]).
    float g[WS];
    {
        const float g5  = sqrtf(window[5 * WS + 5]);
        const float inv = 1.0f / g5;
#pragma unroll
        for (int j = 0; j < WS; ++j) g[j] = window[5 * WS + j] * inv;
    }
    const float C1v = 0.01f * 0.01f;
    const float C2v = 0.03f * 0.03f;

    const float* __restrict__ p1 = img1 + (size_t)bc * (IMG_H * IMG_W);
    const float* __restrict__ p2 = img2 + (size_t)bc * (IMG_H * IMG_W);

    // step-invariant LDS byte offsets
    const unsigned woffA = swz8(col + 6);      // write col   (E = 2t+6)
    const unsigned woffB = swz8(col + 7);      // write col+1 (E = 2t+7)
    const int q  = tid & 127;                  // horizontal: col quad 4q..4q+3
    const int jj = tid >> 7;                   // horizontal: row pair 0/1
    unsigned roff[14];                         // reads: E = 4q+1 .. 4q+14
#pragma unroll
    for (int m = 0; m < 14; ++m) roff[m] = swz8(4 * q + 1 + m);

    // zero halo elements once: E in {0..5, 518..523} per region (96 stores)
    if (tid < 96) {
        const int pj = tid / 12, h = tid % 12;
        const int E  = (h < 6) ? h : (512 + h);
        *(v2f*)(lds + pj * PLANE_B + swz8(E)) = (v2f)(0.0f);
    }
    __syncthreads();

    // raw register ring: slot i holds row R-5+i (after the shift at step base R)
    v2f rx1[RING], rx2[RING];
#pragma unroll
    for (int i = 0; i < RING; ++i) { rx1[i] = (v2f)(0.0f); rx2[i] = (v2f)(0.0f); }

    // warm-up: slots 4..13 <- rows r0-5 .. r0+4
#pragma unroll
    for (int i = 0; i < 10; ++i) {
        const int rr = r0 - PAD + i;
        v2f u1 = (v2f)(0.0f), u2 = (v2f)(0.0f);
        if (rr >= 0 && rr < IMG_H) {               // uniform branch
            u1 = *(const v2f*)(p1 + rr * IMG_W + col);
            u2 = *(const v2f*)(p2 + rr * IMG_W + col);
        }
        rx1[4 + i] = u1; rx2[4 + i] = u2;
    }

    float acc = 0.0f;

    for (int step = 0; step < CHUNK / 4; ++step) {
        const int R = r0 + step * 4;           // output rows R..R+3 this step

        // shift ring by 4
#pragma unroll
        for (int i = 0; i < RING - 4; ++i) { rx1[i] = rx1[i + 4]; rx2[i] = rx2[i + 4]; }
        // load rows R+5..R+8 -> slots 10..13
#pragma unroll
        for (int j = 0; j < 4; ++j) {
            const int rr = R + PAD + j;
            v2f u1 = (v2f)(0.0f), u2 = (v2f)(0.0f);
            if (rr < IMG_H) {                  // uniform branch
                u1 = *(const v2f*)(p1 + rr * IMG_W + col);
                u2 = *(const v2f*)(p2 + rr * IMG_W + col);
            }
            rx1[10 + j] = u1; rx2[10 + j] = u2;
        }

        // vertical gaussian sums: 4 planes x 4 rows, packed over the col pair.
        // (X1*X1+X2*X2 and X1*X2 per slot are CSE'd across the 4 rows.)
        v2f va[4][4];
#pragma unroll
        for (int p = 0; p < 4; ++p)
#pragma unroll
            for (int k = 0; k < 4; ++k) va[p][k] = (v2f)(0.0f);
#pragma unroll
        for (int k = 0; k < 4; ++k) {
#pragma unroll
            for (int i = 0; i < WS; ++i) {
                const v2f w  = (v2f)(g[i]);
                const v2f X1 = rx1[i + k], X2 = rx2[i + k];
                va[0][k] = vfma(w, X1, va[0][k]);
                va[1][k] = vfma(w, X2, va[1][k]);
                va[2][k] = vfma(w, vfma(X1, X1, X2 * X2), va[2][k]);
                va[3][k] = vfma(w, X1 * X2, va[3][k]);
            }
        }
        // repack {col-packed rows} -> {row-pair packed cols} and store
#pragma unroll
        for (int jp = 0; jp < 2; ++jp) {
#pragma unroll
            for (int p = 0; p < 4; ++p) {
                char* base = lds + (jp * 4 + p) * PLANE_B;
                *(v2f*)(base + woffA) = (v2f){va[p][2 * jp].x, va[p][2 * jp + 1].x};
                *(v2f*)(base + woffB) = (v2f){va[p][2 * jp].y, va[p][2 * jp + 1].y};
            }
        }
        __syncthreads();

        // horizontal conv + SSIM: 4 cols (quad q), row pair jj (rows R+2jj, +1)
        v2f h[4][4];                           // [plane][d]
#pragma unroll
        for (int p = 0; p < 4; ++p) {
            const char* base = lds + (jj * 4 + p) * PLANE_B;
            v2f r[14];
#pragma unroll
            for (int m = 0; m < 14; ++m) r[m] = *(const v2f*)(base + roff[m]);
#pragma unroll
            for (int d = 0; d < 4; ++d) {
                v2f s = (v2f)(0.0f);
#pragma unroll
                for (int i = 0; i < WS; ++i) s = vfma((v2f)(g[i]), r[d + i], s);
                h[p][d] = s;
            }
        }
#pragma unroll
        for (int d = 0; d < 4; ++d) {
            const v2f mu1 = h[0][d], mu2 = h[1][d];
            const v2f hs  = h[2][d], hp  = h[3][d];
            const v2f mu1s = mu1 * mu1;
            const v2f mu2s = mu2 * mu2;
            const v2f mu12 = mu1 * mu2;
            const v2f sgs  = hs - mu1s - mu2s;       // sigma1^2 + sigma2^2
            const v2f sg12 = hp - mu12;
            const v2f num  = (2.f * mu12 + (v2f)(C1v)) * (2.f * sg12 + (v2f)(C2v));
            const v2f den  = (mu1s + mu2s + (v2f)(C1v)) * (sgs + (v2f)(C2v));
            v2f r = {__builtin_amdgcn_rcpf(den.x), __builtin_amdgcn_rcpf(den.y)};
            r = r * vfma(-den, r, (v2f)(2.0f));      // Newton -> ~1 ulp
            acc = fmaf(num.x, r.x, acc);
            acc = fmaf(num.y, r.y, acc);
        }
        __syncthreads();   // before LDS is overwritten next step
    }

    // block reduction -> single atomic per block (pre-scaled by 1/Npx)
#pragma unroll
    for (int off = 32; off > 0; off >>= 1)
        acc += __shfl_down(acc, off);
    if ((tid & 63) == 0) wred[tid >> 6] = acc;
    __syncthreads();
    if (tid == 0) {
        const float s = (wred[0] + wred[1]) + (wred[2] + wred[3]);
        atomicAdd(out, s * INV_NPX);
    }
}

extern "C" void kernel_launch(void* const* d_in, const int* in_sizes, int n_in,
                              void* d_out, int out_size, void* d_ws, size_t ws_size,
                              hipStream_t stream) {
    const float* img1   = (const float*)d_in[0];
    const float* img2   = (const float*)d_in[1];
    const float* window = (const float*)d_in[2];
    float* out = (float*)d_out;

    hipMemsetAsync(out, 0, sizeof(float), stream);   // graph-capturable
    dim3 grid(N_IMG, NCHUNK);
    ssim_partial_kernel<<<grid, 256, 0, stream>>>(img1, img2, window, out);
}